// Round 1
// 901.237 us; speedup vs baseline: 1.0001x; 1.0001x over previous
//
#include <hip/hip_runtime.h>
#include <hip/hip_bf16.h>
#include <stdint.h>

// Problem constants
#define M_ROWS 4096
#define N_OUT  1024
#define K_IN   1024
#define MASK_N 134217728   // 512^3
#define MASK_BLOCKS 16384  // mask portion of the fused grid

typedef __attribute__((ext_vector_type(8))) short bf16x8;
typedef __attribute__((ext_vector_type(4))) float f32x4;
typedef float f4v __attribute__((ext_vector_type(4)));

// ---------- fp32 -> bf16 round-to-nearest-even ----------
__device__ inline short f2bf(float f) {
    unsigned u = __float_as_uint(f);
    unsigned r = u + 0x7fffu + ((u >> 16) & 1u);
    return (short)(r >> 16);
}

__device__ inline float next_up(float f) {
    unsigned u = __float_as_uint(f);
    if (u == 0x80000000u || u == 0u) return __uint_as_float(0x00000001u);
    if (f > 0.0f) return __uint_as_float(u + 1u);
    return __uint_as_float(u - 1u);
}

// 16B global -> LDS async DMA (wave-uniform base + lane*16 on the LDS side)
__device__ inline void async16(const void* g, void* l) {
    __builtin_amdgcn_global_load_lds(
        (const __attribute__((address_space(1))) unsigned int*)g,
        (__attribute__((address_space(3))) unsigned int*)l, 16, 0, 0);
}

// ---------- Kernel 1: fused fp32->bf16 convert (XOR-swizzled layout) + column sums ----------
// blocks 0..255  : input rows 16b..16b+15
// blocks 256..319: weight rows 16(b-256)..+15
// thread t owns cols 4t..4t+3 (float4 read, short4 swizzled write, fp64 col partials)
// Swizzle: orig element (R, kc*32 + c*8 + j) stored at col kc*32 + (c ^ ((R>>1)&3))*8 + j.
__global__ __launch_bounds__(256) void conv_colsum_kernel(
    const float* __restrict__ input, const float* __restrict__ weight,
    short* __restrict__ in_bf, short* __restrict__ w_bf,
    double* __restrict__ s_in, double* __restrict__ w_sum)
{
    int b = blockIdx.x;
    int t = threadIdx.x;
    const float* src; short* dst; double* sums; int row0;
    if (b < 256) { src = input;  dst = in_bf; sums = s_in;  row0 = b * 16; }
    else         { src = weight; dst = w_bf;  sums = w_sum; row0 = (b - 256) * 16; }

    const int kc = t >> 3;          // 32-col block
    const int c  = (t >> 1) & 3;    // 8-col chunk within block
    const int j0 = (t & 1) << 2;    // 4-col half within chunk

    double a0 = 0, a1 = 0, a2 = 0, a3 = 0;
    for (int r = 0; r < 16; ++r) {
        int R = row0 + r;
        float4 v = *(const float4*)&src[(size_t)R * 1024 + 4 * t];
        int sc = c ^ ((R >> 1) & 3);
        short4 s4 = { f2bf(v.x), f2bf(v.y), f2bf(v.z), f2bf(v.w) };
        *(short4*)&dst[(size_t)R * 1024 + (kc << 5) + (sc << 3) + j0] = s4;
        a0 += (double)v.x; a1 += (double)v.y; a2 += (double)v.z; a3 += (double)v.w;
    }
    int c0 = 4 * t;
    atomicAdd(&sums[c0 + 0], a0);
    atomicAdd(&sums[c0 + 1], a1);
    atomicAdd(&sums[c0 + 2], a2);
    atomicAdd(&sums[c0 + 3], a3);
}

// ---------- Kernel 2: combine to scalar threshold + exact float cut ----------
// threshold = (sum_i s_in[i]*w_sum[i])/4096 + sum_o bias[o]
__global__ __launch_bounds__(1024) void threshold_kernel(
    const double* __restrict__ s_in, const double* __restrict__ w_sum,
    const float* __restrict__ bias, double* __restrict__ thr, float* __restrict__ cut)
{
    __shared__ double red[1024];
    int t = threadIdx.x;
    double v = s_in[t] * w_sum[t] * (1.0 / 4096.0) + (double)bias[t];
    red[t] = v;
    __syncthreads();
    for (int s = 512; s > 0; s >>= 1) {
        if (t < s) red[t] += red[t + s];
        __syncthreads();
    }
    if (t == 0) {
        double th = red[0];
        *thr = th;
        float f = (float)th;
        if ((double)f <= th) f = next_up(f);
        // f = smallest float with (double)f > th:  (m >= f) <=> ((double)m > th)
        *cut = f;
    }
}

// ---------- Kernel 3 (FUSED): GEMM blocks 0..255 + mask blocks 256..16639 ----------
// GEMM and mask are mutually independent (both only need the threshold stage),
// so they share one launch: GEMM's ~20-50 us hides entirely under the mask
// kernel's ~175 us of HBM streaming. Blocks 0..255 dispatch first, so each CU
// gets one GEMM block (MFMA pipe) plus ~3 mask blocks (memory pipe).
__global__ __launch_bounds__(256) void gemm_mask_kernel(
    const short* __restrict__ Abf,   // input bf16 [4096][1024] swizzled
    const short* __restrict__ Wbf,   // weight bf16 [1024][1024] swizzled
    const float* __restrict__ bias,
    float* __restrict__ C,           // out fp32 [4096][1024]
    const f4v* __restrict__ mask,
    f4v* __restrict__ hi,
    const float* __restrict__ cut_p)
{
    if (blockIdx.x >= 256) {
        // ---- mask path: 16384 blocks x 256 threads x 8 float4 = 512^3 elems ----
        float cut = *cut_p;
        const size_t stride = (size_t)MASK_BLOCKS * 256;
        size_t i0 = (size_t)(blockIdx.x - 256) * 256 + threadIdx.x;
        f4v m[8];
        // batch all 8 nontemporal loads first: 8 loads in flight per lane
        #pragma unroll
        for (int j = 0; j < 8; ++j)
            m[j] = __builtin_nontemporal_load(&mask[i0 + (size_t)j * stride]);
        #pragma unroll
        for (int j = 0; j < 8; ++j) {
            f4v o;
            o.x = (m[j].x >= cut) ? 1.0f : 0.0f;
            o.y = (m[j].y >= cut) ? 1.0f : 0.0f;
            o.z = (m[j].z >= cut) ? 1.0f : 0.0f;
            o.w = (m[j].w >= cut) ? 1.0f : 0.0f;
            __builtin_nontemporal_store(o, &hi[i0 + (size_t)j * stride]);
        }
        return;
    }

    // ---- GEMM path: bf16 MFMA (m97 structure), 128x128 tile, BK=32 ----
    __shared__ short As[128 * 32];   // 8 KB, no padding (DMA constraint); XOR swizzle in layout
    __shared__ short Bs[128 * 32];

    const int tid  = threadIdx.x;
    const int wave = tid >> 6;
    const int lane = tid & 63;
    const int quad = lane >> 4;
    const int l16  = lane & 15;
    const int wr   = (wave >> 1) * 64;
    const int wc   = (wave & 1) * 64;

    const int tile_m = (blockIdx.x >> 3) * 128;  // 32 row tiles
    const int tile_n = (blockIdx.x & 7) * 128;   // 8 col tiles

    f32x4 acc[4][4];
    for (int i = 0; i < 4; ++i)
        for (int j = 0; j < 4; ++j)
            acc[i][j] = (f32x4){0.f, 0.f, 0.f, 0.f};

    // staging addresses: thread tid covers row tid>>2 (+64 for 2nd issue), chunk tid&3
    const short* gA = Abf + (size_t)(tile_m + (tid >> 2)) * 1024 + ((tid & 3) << 3);
    const short* gB = Wbf + (size_t)(tile_n + (tid >> 2)) * 1024 + ((tid & 3) << 3);
    short* lA = &As[tid * 8];     // per-wave linear: base + lane*16 B
    short* lB = &Bs[tid * 8];

    for (int k0 = 0; k0 < K_IN; k0 += 32) {
        async16(gA + k0,             lA);
        async16(gA + 64 * 1024 + k0, lA + 64 * 32);
        async16(gB + k0,             lB);
        async16(gB + 64 * 1024 + k0, lB + 64 * 32);
        __syncthreads();   // compiler emits vmcnt(0) drain before barrier

        bf16x8 af[4], bfr[4];
        for (int i = 0; i < 4; ++i) {
            int ra = wr + i * 16 + l16;
            af[i]  = *(const bf16x8*)&As[ra * 32 + ((quad ^ ((ra >> 1) & 3)) << 3)];
            int rb = wc + i * 16 + l16;
            bfr[i] = *(const bf16x8*)&Bs[rb * 32 + ((quad ^ ((rb >> 1) & 3)) << 3)];
        }
        for (int i = 0; i < 4; ++i)
            for (int j = 0; j < 4; ++j)
                acc[i][j] = __builtin_amdgcn_mfma_f32_16x16x32_bf16(
                    af[i], bfr[j], acc[i][j], 0, 0, 0);
        __syncthreads();
    }

    for (int i = 0; i < 4; ++i) {
        for (int j = 0; j < 4; ++j) {
            int col = tile_n + wc + j * 16 + l16;
            float b = bias[col];
            for (int r = 0; r < 4; ++r) {
                int row = tile_m + wr + i * 16 + quad * 4 + r;
                C[(size_t)row * N_OUT + col] = acc[i][j][r] + b;
            }
        }
    }
}

extern "C" void kernel_launch(void* const* d_in, const int* in_sizes, int n_in,
                              void* d_out, int out_size, void* d_ws, size_t ws_size,
                              hipStream_t stream) {
    const float* input  = (const float*)d_in[0];   // [4096,1024]
    const float* mask   = (const float*)d_in[1];   // [512,512,512]
    const float* weight = (const float*)d_in[2];   // [1024,1024]
    const float* bias   = (const float*)d_in[3];   // [1024]

    float* out = (float*)d_out;                          // [4096,1024]
    float* hi  = out + (size_t)M_ROWS * N_OUT;           // [512^3] as 0/1 floats

    // workspace layout (bytes):
    //   0      : s_in   [1024] double  (8 KB)
    //   8192   : w_sum  [1024] double  (8 KB)
    //   16384  : thr (double), cut (float)
    //   32768  : in_bf  [4096*1024] bf16 (8 MB)
    //   8421376: w_bf   [1024*1024] bf16 (2 MB)
    char* wsb = (char*)d_ws;
    double* s_in  = (double*)wsb;
    double* w_sum = (double*)(wsb + 8192);
    double* thr   = (double*)(wsb + 16384);
    float*  cut   = (float*)(wsb + 16384 + 8);
    short*  in_bf = (short*)(wsb + 32768);
    short*  w_bf  = (short*)(wsb + 32768 + (size_t)M_ROWS * K_IN * 2);

    // zero the fp64 accumulators (ws is poisoned 0xAA before every launch)
    hipMemsetAsync(d_ws, 0, 16384, stream);

    conv_colsum_kernel<<<320, 256, 0, stream>>>(input, weight, in_bf, w_bf, s_in, w_sum);
    threshold_kernel<<<1, 1024, 0, stream>>>(s_in, w_sum, bias, thr, cut);
    gemm_mask_kernel<<<256 + MASK_BLOCKS, 256, 0, stream>>>(
        in_bf, w_bf, bias, out, (const f4v*)mask, (f4v*)hi, cut);
}